// Round 9
// baseline (105.860 us; speedup 1.0000x reference)
//
#include <hip/hip_runtime.h>
#include <hip/hip_bf16.h>

#define ALPHA 0.2f
#define NROW 8192

typedef __attribute__((ext_vector_type(4))) float f4;
typedef __attribute__((ext_vector_type(8))) short s8;
typedef __attribute__((ext_vector_type(4))) unsigned u4;

__device__ __forceinline__ short f2bf_bits(float x){
    __hip_bfloat16 b = __float2bfloat16(x);
    return __builtin_bit_cast(short, b);
}

// K1: h = x@W ; s1 ; s2 ; F1=exp(s2) ; F2=exp(0.2*s2) ;
// hpack = h in MFMA B-fragment order: element ((sc*4+fg)*64 + hg*16 + lr)*8 + e
//   = h[j = sc*32 + hg*8 + e][f = fg*16 + lr]  (bf16)
__global__ __launch_bounds__(256) void k_proj(
    const float* __restrict__ x, const float* __restrict__ W, const float* __restrict__ a,
    float* __restrict__ s1, float* __restrict__ s2,
    float* __restrict__ F1, float* __restrict__ F2, __hip_bfloat16* __restrict__ hpack)
{
    __shared__ float Wsh[128*64];
    __shared__ float xsh[4*128];
    const int t = threadIdx.x;
    const int f = t & 63, ry = t >> 6;
    const int row0 = blockIdx.x * 4;
    for (int i = t; i < 128*64; i += 256) Wsh[i] = W[i];
    for (int i = t; i < 4*128; i += 256) xsh[i] = x[row0*128 + i];
    __syncthreads();
    float acc = 0.f;
    #pragma unroll
    for (int k = 0; k < 128; ++k) acc = fmaf(xsh[ry*128 + k], Wsh[k*64 + f], acc);
    float p1 = acc * a[f], p2 = acc * a[64 + f];
    #pragma unroll
    for (int m = 32; m; m >>= 1){ p1 += __shfl_xor(p1, m, 64); p2 += __shfl_xor(p2, m, 64); }
    const int j = row0 + ry;
    if (f == 0){
        s1[j] = p1; s2[j] = p2;
        F1[j] = __expf(p2); F2[j] = __expf(0.2f * p2);
    }
    const int sc = j >> 5, hg = (j >> 3) & 3, e = j & 7;
    const int fg = f >> 4, lr = f & 15;
    hpack[(((sc*4 + fg)*64) + hg*16 + lr)*8 + e] = __float2bfloat16(acc);
}

// K2: s2max = max(s2)
__global__ __launch_bounds__(1024) void k_s2max(const float* __restrict__ s2, float* __restrict__ s2max)
{
    __shared__ float red[1024];
    float m = -1e30f;
    for (int i = threadIdx.x; i < NROW; i += 1024) m = fmaxf(m, s2[i]);
    red[threadIdx.x] = m; __syncthreads();
    for (int s = 512; s; s >>= 1){
        if (threadIdx.x < (unsigned)s) red[threadIdx.x] = fmaxf(red[threadIdx.x], red[threadIdx.x + s]);
        __syncthreads();
    }
    if (threadIdx.x == 0) s2max[0] = red[0];
}

// K3: barrier-free fused stream. Wave w owns j-window [w*1024,(w+1)*1024):
//  - A(sub): 8 coalesced loads (2 rows x 128 cols each) -> 32 ballots ->
//    wave-private swizzled LDS mask (16 rows x 16B per sub)
//  - B(sub): 4 MFMA STEPs consuming own mask + fragment-packed h (L2) + F (L2)
// No __syncthreads in the stream; waves slip freely; HBM busy end-to-end.
__global__ __launch_bounds__(512, 4) void k_attn8(
    const float* __restrict__ adj, const float* __restrict__ s1g,
    const float* __restrict__ s2maxp, const float* __restrict__ F1g,
    const float* __restrict__ F2g, const __hip_bfloat16* __restrict__ hpack,
    float* __restrict__ out)
{
    __shared__ __attribute__((aligned(16))) char arena[33280];
    // stream phase: [wave][2KB] mask regions (16 KB). epilogue: accb 32KB + lsb.

    const int tid = threadIdx.x;
    const int w = tid >> 6, lane = tid & 63;
    const int lr = lane & 15, hi = lane >> 4;
    const int i0 = blockIdx.x * 16, row = i0 + lr;

    const float s1r = s1g[row];
    const float t0 = s1r + s2maxp[0];
    const float Mr = fmaxf(t0, ALPHA * t0);      // >= true row max of lrelu logits
    const float E1 = __expf(s1r - Mr);           // t>0:  p = E1*F1_j
    const float E2 = __expf(ALPHA * s1r - Mr);   // t<=0: p = E2*F2_j
    const float T1 = __expf(-s1r);               // (t>0) <=> F1_j > T1

    const int jw = w * 1024;
    const int half = lane >> 5, sl = lane & 31;
    // producer base: row (i0 + half + 2*rp), cols jw + s*128 + sl*4 + e
    const float* pA = adj + (long)(i0 + half) * NROW + jw + sl * 4;
    char* wmask = arena + w * 2048;

    const s8* hpb = (const s8*)hpack + (w*32)*4*64 + lane;   // + t*256 + fg*64
    const float* f1p = F1g + jw + hi * 8;
    const float* f2p = F2g + jw + hi * 8;

    f4 acc0 = {0.f,0.f,0.f,0.f}, acc1 = {0.f,0.f,0.f,0.f};
    f4 acc2 = {0.f,0.f,0.f,0.f}, acc3 = {0.f,0.f,0.f,0.f};
    float lsum = 0.f;

    f4 v0,v1,v2,v3,v4,v5,v6,v7;   // single 32-VGPR slot (8 row-pair loads)

#define ALOAD(s) do { \
    const float* ps = pA + (s) * 128; \
    v0 = *(const f4*)(ps);                 v1 = *(const f4*)(ps + 2*NROW); \
    v2 = *(const f4*)(ps + 4*NROW);        v3 = *(const f4*)(ps + 6*NROW); \
    v4 = *(const f4*)(ps + 8*NROW);        v5 = *(const f4*)(ps + 10*NROW); \
    v6 = *(const f4*)(ps + 12*NROW);       v7 = *(const f4*)(ps + 14*NROW); \
} while(0)

// ballot 4 elems of one row-pair load, 2 lanes store 16B each into wave LDS
#define BST(vv, rp, s) do { \
    unsigned long long b0 = __ballot((vv)[0] > 0.f); \
    unsigned long long b1 = __ballot((vv)[1] > 0.f); \
    unsigned long long b2 = __ballot((vv)[2] > 0.f); \
    unsigned long long b3 = __ballot((vv)[3] > 0.f); \
    if (sl == 0){ \
        const int r_ = 2*(rp) + half; \
        const unsigned sh_ = half ? 32u : 0u; \
        *(u4*)(wmask + r_*128 + (((s) ^ (r_ & 7)) << 4)) = \
            (u4){(unsigned)(b0>>sh_), (unsigned)(b1>>sh_), \
                 (unsigned)(b2>>sh_), (unsigned)(b3>>sh_)}; \
    } } while(0)

#define BSTORE(s) do { \
    BST(v0, 0, s); BST(v1, 1, s); BST(v2, 2, s); BST(v3, 3, s); \
    BST(v4, 4, s); BST(v5, 5, s); BST(v6, 6, s); BST(v7, 7, s); \
} while(0)

#define CALCQ(cond, g1, g2, qd) { \
    float fz = ((g1) > T1) ? (g1) * E1 : (g2) * E2; \
    qd = (cond) ? fz : 0.f; }

#define STEP(s, q) do { \
    const int t_ = (s)*4 + (q); \
    u4 mq = *(const u4*)(wmask + lr*128 + (((s) ^ (lr & 7)) << 4)); \
    const float* f1_ = f1p + t_*32; \
    const float* f2_ = f2p + t_*32; \
    f4 f1a = *(const f4*)(f1_); f4 f1b = *(const f4*)(f1_ + 4); \
    f4 f2a = *(const f4*)(f2_); f4 f2b = *(const f4*)(f2_ + 4); \
    s8 h0 = hpb[t_*256];       s8 h1 = hpb[t_*256 + 64]; \
    s8 h2 = hpb[t_*256 + 128]; s8 h3 = hpb[t_*256 + 192]; \
    const unsigned sh = (q)*8 + hi*2; \
    const unsigned b0 = mq[0] >> sh, b1 = mq[1] >> sh; \
    const unsigned b2 = mq[2] >> sh, b3 = mq[3] >> sh; \
    float q0,q1,q2,q3,q4,q5,q6,q7; \
    CALCQ(b0 & 1u, f1a[0], f2a[0], q0); CALCQ(b1 & 1u, f1a[1], f2a[1], q1); \
    CALCQ(b2 & 1u, f1a[2], f2a[2], q2); CALCQ(b3 & 1u, f1a[3], f2a[3], q3); \
    CALCQ(b0 & 2u, f1b[0], f2b[0], q4); CALCQ(b1 & 2u, f1b[1], f2b[1], q5); \
    CALCQ(b2 & 2u, f1b[2], f2b[2], q6); CALCQ(b3 & 2u, f1b[3], f2b[3], q7); \
    lsum += ((q0+q1)+(q2+q3)) + ((q4+q5)+(q6+q7)); \
    s8 af; \
    af[0]=f2bf_bits(q0); af[1]=f2bf_bits(q1); af[2]=f2bf_bits(q2); af[3]=f2bf_bits(q3); \
    af[4]=f2bf_bits(q4); af[5]=f2bf_bits(q5); af[6]=f2bf_bits(q6); af[7]=f2bf_bits(q7); \
    acc0 = __builtin_amdgcn_mfma_f32_16x16x32_bf16(af, h0, acc0, 0, 0, 0); \
    acc1 = __builtin_amdgcn_mfma_f32_16x16x32_bf16(af, h1, acc1, 0, 0, 0); \
    acc2 = __builtin_amdgcn_mfma_f32_16x16x32_bf16(af, h2, acc2, 0, 0, 0); \
    acc3 = __builtin_amdgcn_mfma_f32_16x16x32_bf16(af, h3, acc3, 0, 0, 0); \
} while(0)

    // prologue: mask(0) ready, loads for sub 1 in flight
    ALOAD(0); BSTORE(0);
    ALOAD(1);
    #pragma unroll 1
    for (int s = 0; s < 8; ++s){
        if (s < 7) BSTORE(s + 1);        // consume slot (loaded last iter)
        if (s < 6) ALOAD(s + 2);         // reissue slot; in flight across STEPs
        STEP(s, 0); STEP(s, 1); STEP(s, 2); STEP(s, 3);
    }
#undef ALOAD
#undef BST
#undef BSTORE
#undef CALCQ
#undef STEP

    lsum += __shfl_xor(lsum, 16, 64);
    lsum += __shfl_xor(lsum, 32, 64);

    __syncthreads();   // all waves done streaming -> reuse arena for epilogue
    float* accb = (float*)arena;               // [8][16][64] = 32 KB
    float* lsb  = (float*)(arena + 32768);     // [8][16]

    // C layout: col = lane&15, row = (lane>>4)*4 + reg
    #pragma unroll
    for (int r = 0; r < 4; ++r){
        accb[((w*16 + hi*4 + r) << 6) +  0 + lr] = acc0[r];
        accb[((w*16 + hi*4 + r) << 6) + 16 + lr] = acc1[r];
        accb[((w*16 + hi*4 + r) << 6) + 32 + lr] = acc2[r];
        accb[((w*16 + hi*4 + r) << 6) + 48 + lr] = acc3[r];
    }
    if (lane < 16) lsb[w*16 + lane] = lsum;
    __syncthreads();

    for (int idx = tid; idx < 1024; idx += 512){
        int r = idx >> 6, cf = idx & 63;
        float sa = 0.f, L = 0.f;
        #pragma unroll
        for (int ww = 0; ww < 8; ++ww){ sa += accb[((ww*16 + r) << 6) + cf]; L += lsb[ww*16 + r]; }
        float v = sa / L;
        out[(long)(i0 + r) * 64 + cf] = (v > 0.f) ? v : expm1f(v);
    }
}

extern "C" void kernel_launch(void* const* d_in, const int* in_sizes, int n_in,
                              void* d_out, int out_size, void* d_ws, size_t ws_size,
                              hipStream_t stream)
{
    const float* x   = (const float*)d_in[0];
    const float* adj = (const float*)d_in[1];
    const float* W   = (const float*)d_in[2];
    const float* a   = (const float*)d_in[3];
    float* out = (float*)d_out;

    char* ws = (char*)d_ws;
    float* s1   = (float*)(ws);                    // 32 KB
    float* s2   = (float*)(ws + 32768);            // 32 KB
    float* F1   = (float*)(ws + 65536);            // 32 KB
    float* F2   = (float*)(ws + 98304);            // 32 KB
    float* s2mx = (float*)(ws + 131072);           // 256 B
    __hip_bfloat16* hpack = (__hip_bfloat16*)(ws + 131328);   // 1 MB

    k_proj <<<2048,  256, 0, stream>>>(x, W, a, s1, s2, F1, F2, hpack);
    k_s2max<<<   1, 1024, 0, stream>>>(s2, s2mx);
    k_attn8<<< 512,  512, 0, stream>>>(adj, s1, s2mx, F1, F2, hpack, out);
}

// Round 10
// 79.291 us; speedup vs baseline: 1.3351x; 1.3351x over previous
//
#include <hip/hip_runtime.h>
#include <hip/hip_bf16.h>

#define ALPHA 0.2f
#define NROW 8192

typedef __attribute__((ext_vector_type(4))) float f4;
typedef __attribute__((ext_vector_type(8))) short s8;

__device__ __forceinline__ short f2bf_bits(float x){
    __hip_bfloat16 b = __float2bfloat16(x);
    return __builtin_bit_cast(short, b);
}

__device__ __forceinline__ void gload_lds16(const void* g, void* l){
    __builtin_amdgcn_global_load_lds(
        (const __attribute__((address_space(1))) void*)g,
        (__attribute__((address_space(3))) void*)l, 16, 0, 0);
}

// K1: h = x@W ; s1 ; s2 ; F1=exp(s2) ; F2=exp(0.2*s2) ;
// hpack = h in MFMA B-fragment order: s8-elem (sc*4+fg)*64 + (hg*16+lr), lane elem e
//   = h[j = sc*32 + hg*8 + e][f = fg*16 + lr]  (bf16)
__global__ __launch_bounds__(256) void k_proj(
    const float* __restrict__ x, const float* __restrict__ W, const float* __restrict__ a,
    float* __restrict__ s1, float* __restrict__ s2,
    float* __restrict__ F1, float* __restrict__ F2, __hip_bfloat16* __restrict__ hpack)
{
    __shared__ float Wsh[128*64];
    __shared__ float xsh[4*128];
    const int t = threadIdx.x;
    const int f = t & 63, ry = t >> 6;
    const int row0 = blockIdx.x * 4;
    for (int i = t; i < 128*64; i += 256) Wsh[i] = W[i];
    for (int i = t; i < 4*128; i += 256) xsh[i] = x[row0*128 + i];
    __syncthreads();
    float acc = 0.f;
    #pragma unroll
    for (int k = 0; k < 128; ++k) acc = fmaf(xsh[ry*128 + k], Wsh[k*64 + f], acc);
    float p1 = acc * a[f], p2 = acc * a[64 + f];
    #pragma unroll
    for (int m = 32; m; m >>= 1){ p1 += __shfl_xor(p1, m, 64); p2 += __shfl_xor(p2, m, 64); }
    const int j = row0 + ry;
    if (f == 0){
        s1[j] = p1; s2[j] = p2;
        F1[j] = __expf(p2); F2[j] = __expf(0.2f * p2);
    }
    const int sc = j >> 5, hg = (j >> 3) & 3, e = j & 7;
    const int fg = f >> 4, lr = f & 15;
    hpack[(((sc*4 + fg)*64) + hg*16 + lr)*8 + e] = __float2bfloat16(acc);
}

// K2: s2max = max(s2)
__global__ __launch_bounds__(1024) void k_s2max(const float* __restrict__ s2, float* __restrict__ s2max)
{
    __shared__ float red[1024];
    float m = -1e30f;
    for (int i = threadIdx.x; i < NROW; i += 1024) m = fmaxf(m, s2[i]);
    red[threadIdx.x] = m; __syncthreads();
    for (int s = 512; s; s >>= 1){
        if (threadIdx.x < (unsigned)s) red[threadIdx.x] = fmaxf(red[threadIdx.x], red[threadIdx.x + s]);
        __syncthreads();
    }
    if (threadIdx.x == 0) s2max[0] = red[0];
}

// K3: block = (jslab: 1024 cols) x (igrp: 256 rows). h-slab + F in LDS (136 KB).
// Loop's ONLY global traffic = 2 coalesced adj loads/step, counted vmcnt(6),
// mask via in-register ballots. Wave owns i-tiles w and w+8 (acc A/B).
__global__ __launch_bounds__(512, 2) void k_gat(
    const float* __restrict__ adj, const float* __restrict__ s1g,
    const float* __restrict__ s2maxp, const float* __restrict__ F1g,
    const float* __restrict__ F2g, const __hip_bfloat16* __restrict__ hpack,
    float* __restrict__ part, float* __restrict__ pden)
{
    __shared__ __attribute__((aligned(16))) char arena[139264]; // 128K hsl + 4K F1 + 4K F2

    const int tid = threadIdx.x;
    const int w = tid >> 6, lane = tid & 63;
    const int lr = lane & 15, hi = lane >> 4;
    const int jslab = blockIdx.x >> 5, igrp = blockIdx.x & 31;

    const s8* hsl = (const s8*)arena;
    float* F1sl = (float*)(arena + 131072);
    float* F2sl = (float*)(arena + 135168);

    // per-tile row constants (tiles A: rows rbA+0..15, B: rbA+128..143)
    const int rbA = igrp*256 + w*16;
    const int rowA = rbA + lr, rowB = rowA + 128;
    const float s2m = s2maxp[0];
    const float s1A = s1g[rowA], s1B = s1g[rowB];
    float tA = s1A + s2m, tB = s1B + s2m;
    const float MrA = fmaxf(tA, ALPHA*tA), MrB = fmaxf(tB, ALPHA*tB);
    const float E1A = __expf(s1A - MrA), E2A = __expf(ALPHA*s1A - MrA), T1A = __expf(-s1A);
    const float E1B = __expf(s1B - MrB), E2B = __expf(ALPHA*s1B - MrB), T1B = __expf(-s1B);

    // stage h-slab (128 KB) via global_load_lds + F (8 KB) via regs
    {
        const s8* hp = (const s8*)hpack + jslab*8192;
        #pragma unroll
        for (int it = 0; it < 16; ++it)
            gload_lds16(hp + w*1024 + it*64 + lane, arena + (w*1024 + it*64)*16);
        #pragma unroll
        for (int k = 0; k < 2; ++k){
            F1sl[tid + k*512] = F1g[jslab*1024 + tid + k*512];
            F2sl[tid + k*512] = F2g[jslab*1024 + tid + k*512];
        }
    }
    __syncthreads();   // drains staging; last barrier in the kernel

    // adj per-lane producer pointer: rows rbA + (lane>>3) (+8 for 2nd load), cols (lane&7)*4
    const float* padj = adj + (long)(rbA + (lane >> 3))*NROW + jslab*1024 + (lane & 7)*4;
    const unsigned bsh = (unsigned)((lr & 7)*8 + hi*2);
    const int hi8 = hi * 8;

    f4 acc0A={0,0,0,0}, acc1A={0,0,0,0}, acc2A={0,0,0,0}, acc3A={0,0,0,0};
    f4 acc0B={0,0,0,0}, acc1B={0,0,0,0}, acc2B={0,0,0,0}, acc3B={0,0,0,0};
    float lsumA = 0.f, lsumB = 0.f;

    f4 v0S0,v1S0, v0S1,v1S1, v0S2,v1S2, v0S3,v1S3;

#define LOAD(S, st_) do { \
    const long o_ = (long)(((st_) >> 5) * (128*NROW)) + (((st_) & 31) * 32); \
    v0##S = *(const f4*)(padj + o_); \
    v1##S = *(const f4*)(padj + o_ + 8*NROW); \
} while(0)

#define CALCQ(X, cond, g1, g2, qd) { \
    float fz = ((g1) > T1##X) ? (g1) * E1##X : (g2) * E2##X; \
    qd = (cond) ? fz : 0.f; }

#define STEP(X, S, st_) do { \
    unsigned long long c0_ = __ballot(v0##S[0] > 0.f); \
    unsigned long long c1_ = __ballot(v0##S[1] > 0.f); \
    unsigned long long c2_ = __ballot(v0##S[2] > 0.f); \
    unsigned long long c3_ = __ballot(v0##S[3] > 0.f); \
    unsigned long long d0_ = __ballot(v1##S[0] > 0.f); \
    unsigned long long d1_ = __ballot(v1##S[1] > 0.f); \
    unsigned long long d2_ = __ballot(v1##S[2] > 0.f); \
    unsigned long long d3_ = __ballot(v1##S[3] > 0.f); \
    const unsigned u0 = (unsigned)(((lr < 8) ? c0_ : d0_) >> bsh); \
    const unsigned u1 = (unsigned)(((lr < 8) ? c1_ : d1_) >> bsh); \
    const unsigned u2 = (unsigned)(((lr < 8) ? c2_ : d2_) >> bsh); \
    const unsigned u3 = (unsigned)(((lr < 8) ? c3_ : d3_) >> bsh); \
    const int t_ = (st_) & 31; \
    const s8* hb_ = hsl + t_*256; \
    s8 h0 = hb_[lane]; s8 h1 = hb_[64 + lane]; \
    s8 h2 = hb_[128 + lane]; s8 h3 = hb_[192 + lane]; \
    f4 f1a = *(const f4*)&F1sl[t_*32 + hi8]; f4 f1b = *(const f4*)&F1sl[t_*32 + hi8 + 4]; \
    f4 f2a = *(const f4*)&F2sl[t_*32 + hi8]; f4 f2b = *(const f4*)&F2sl[t_*32 + hi8 + 4]; \
    float q0,q1,q2,q3,q4,q5,q6,q7; \
    CALCQ(X, u0 & 1u, f1a[0], f2a[0], q0); CALCQ(X, u1 & 1u, f1a[1], f2a[1], q1); \
    CALCQ(X, u2 & 1u, f1a[2], f2a[2], q2); CALCQ(X, u3 & 1u, f1a[3], f2a[3], q3); \
    CALCQ(X, u0 & 2u, f1b[0], f2b[0], q4); CALCQ(X, u1 & 2u, f1b[1], f2b[1], q5); \
    CALCQ(X, u2 & 2u, f1b[2], f2b[2], q6); CALCQ(X, u3 & 2u, f1b[3], f2b[3], q7); \
    lsum##X += ((q0+q1)+(q2+q3)) + ((q4+q5)+(q6+q7)); \
    s8 af; \
    af[0]=f2bf_bits(q0); af[1]=f2bf_bits(q1); af[2]=f2bf_bits(q2); af[3]=f2bf_bits(q3); \
    af[4]=f2bf_bits(q4); af[5]=f2bf_bits(q5); af[6]=f2bf_bits(q6); af[7]=f2bf_bits(q7); \
    acc0##X = __builtin_amdgcn_mfma_f32_16x16x32_bf16(af, h0, acc0##X, 0, 0, 0); \
    acc1##X = __builtin_amdgcn_mfma_f32_16x16x32_bf16(af, h1, acc1##X, 0, 0, 0); \
    acc2##X = __builtin_amdgcn_mfma_f32_16x16x32_bf16(af, h2, acc2##X, 0, 0, 0); \
    acc3##X = __builtin_amdgcn_mfma_f32_16x16x32_bf16(af, h3, acc3##X, 0, 0, 0); \
} while(0)

#define W6 asm volatile("s_waitcnt vmcnt(6)" ::: "memory")
#define W4 asm volatile("s_waitcnt vmcnt(4)" ::: "memory")
#define W2 asm volatile("s_waitcnt vmcnt(2)" ::: "memory")
#define W0 asm volatile("s_waitcnt vmcnt(0)" ::: "memory")

    LOAD(S0, 0); LOAD(S1, 1); LOAD(S2, 2); LOAD(S3, 3);

    #pragma unroll 1
    for (int it = 0; it < 8; ++it){            // steps 0..31 (tile A), loads 4..35
        const int st = it*4;
        W6; STEP(A, S0, st    ); LOAD(S0, st + 4);
        W6; STEP(A, S1, st + 1); LOAD(S1, st + 5);
        W6; STEP(A, S2, st + 2); LOAD(S2, st + 6);
        W6; STEP(A, S3, st + 3); LOAD(S3, st + 7);
    }
    #pragma unroll 1
    for (int it = 8; it < 15; ++it){           // steps 32..59 (tile B), loads 36..63
        const int st = it*4;
        W6; STEP(B, S0, st    ); LOAD(S0, st + 4);
        W6; STEP(B, S1, st + 1); LOAD(S1, st + 5);
        W6; STEP(B, S2, st + 2); LOAD(S2, st + 6);
        W6; STEP(B, S3, st + 3); LOAD(S3, st + 7);
    }
    W6; STEP(B, S0, 60);
    W4; STEP(B, S1, 61);
    W2; STEP(B, S2, 62);
    W0; STEP(B, S3, 63);

#undef LOAD
#undef CALCQ
#undef STEP
#undef W6
#undef W4
#undef W2
#undef W0

    lsumA += __shfl_xor(lsumA, 16, 64); lsumA += __shfl_xor(lsumA, 32, 64);
    lsumB += __shfl_xor(lsumB, 16, 64); lsumB += __shfl_xor(lsumB, 32, 64);

    // partial stores (C layout: col = lr, row = hi*4 + r, col-block q*16)
    {
        const long pbA = ((long)jslab*NROW + rbA + hi*4)*64 + lr;
        const long pbB = pbA + 128L*64;
        #pragma unroll
        for (int r = 0; r < 4; ++r){
            part[pbA + r*64 +  0] = acc0A[r];
            part[pbA + r*64 + 16] = acc1A[r];
            part[pbA + r*64 + 32] = acc2A[r];
            part[pbA + r*64 + 48] = acc3A[r];
            part[pbB + r*64 +  0] = acc0B[r];
            part[pbB + r*64 + 16] = acc1B[r];
            part[pbB + r*64 + 32] = acc2B[r];
            part[pbB + r*64 + 48] = acc3B[r];
        }
        if (lane < 16){
            pden[jslab*NROW + rbA + lr]       = lsumA;
            pden[jslab*NROW + rbA + 128 + lr] = lsumB;
        }
    }
}

// K4: combine 8 jslab partials, divide, ELU, store out.
__global__ __launch_bounds__(256) void k_comb(
    const float* __restrict__ part, const float* __restrict__ pden,
    float* __restrict__ out)
{
    const int idx = blockIdx.x*256 + threadIdx.x;   // 8192*16
    const int i = idx >> 4, c4 = (idx & 15) << 2;
    f4 sa = {0.f,0.f,0.f,0.f}; float L = 0.f;
    #pragma unroll
    for (int s = 0; s < 8; ++s){
        sa += *(const f4*)&part[((long)s*NROW + i)*64 + c4];
        L  += pden[s*NROW + i];
    }
    const float inv = 1.f / L;
    f4 o;
    #pragma unroll
    for (int e = 0; e < 4; ++e){
        float v = sa[e] * inv;
        o[e] = (v > 0.f) ? v : expm1f(v);
    }
    *(f4*)&out[(long)i*64 + c4] = o;
}

extern "C" void kernel_launch(void* const* d_in, const int* in_sizes, int n_in,
                              void* d_out, int out_size, void* d_ws, size_t ws_size,
                              hipStream_t stream)
{
    const float* x   = (const float*)d_in[0];
    const float* adj = (const float*)d_in[1];
    const float* W   = (const float*)d_in[2];
    const float* a   = (const float*)d_in[3];
    float* out = (float*)d_out;

    char* ws = (char*)d_ws;
    float* s1   = (float*)(ws);                    // 32 KB
    float* s2   = (float*)(ws + 32768);            // 32 KB
    float* F1   = (float*)(ws + 65536);            // 32 KB
    float* F2   = (float*)(ws + 98304);            // 32 KB
    float* s2mx = (float*)(ws + 131072);           // 256 B
    __hip_bfloat16* hpack = (__hip_bfloat16*)(ws + 131328);   // 1 MB
    float* part = (float*)(ws + 1179904);          // 16 MB (8 x 8192 x 64)
    float* pden = (float*)(ws + 17957120);         // 256 KB (8 x 8192)

    k_proj <<<2048,  256, 0, stream>>>(x, W, a, s1, s2, F1, F2, hpack);
    k_s2max<<<   1, 1024, 0, stream>>>(s2, s2mx);
    k_gat  <<< 256,  512, 0, stream>>>(adj, s1, s2mx, F1, F2, hpack, part, pden);
    k_comb <<< 512,  256, 0, stream>>>(part, pden, out);
}

// Round 11
// 70.679 us; speedup vs baseline: 1.4978x; 1.1219x over previous
//
#include <hip/hip_runtime.h>
#include <hip/hip_bf16.h>

#define ALPHA 0.2f
#define NROW 8192

typedef __attribute__((ext_vector_type(4))) float f4;
typedef __attribute__((ext_vector_type(8))) short s8;

__device__ __forceinline__ short f2bf_bits(float x){
    __hip_bfloat16 b = __float2bfloat16(x);
    return __builtin_bit_cast(short, b);
}

__device__ __forceinline__ void gload_lds16(const void* g, void* l){
    __builtin_amdgcn_global_load_lds(
        (const __attribute__((address_space(1))) void*)g,
        (__attribute__((address_space(3))) void*)l, 16, 0, 0);
}

// K1: h = x@W ; s1 ; F1=exp(s2) ; F2=exp(0.2*s2) ;
// hpack = h in MFMA B-fragment order: s8-elem (sc*4+fg)*64 + (hg*16+lr), lane elem e
//   = h[j = sc*32 + hg*8 + e][f = fg*16 + lr]  (bf16)
__global__ __launch_bounds__(256) void k_proj(
    const float* __restrict__ x, const float* __restrict__ W, const float* __restrict__ a,
    float* __restrict__ s1,
    float* __restrict__ F1, float* __restrict__ F2, __hip_bfloat16* __restrict__ hpack)
{
    __shared__ float Wsh[128*64];
    __shared__ float xsh[4*128];
    const int t = threadIdx.x;
    const int f = t & 63, ry = t >> 6;
    const int row0 = blockIdx.x * 4;
    for (int i = t; i < 128*64; i += 256) Wsh[i] = W[i];
    for (int i = t; i < 4*128; i += 256) xsh[i] = x[row0*128 + i];
    __syncthreads();
    float acc = 0.f;
    #pragma unroll
    for (int k = 0; k < 128; ++k) acc = fmaf(xsh[ry*128 + k], Wsh[k*64 + f], acc);
    float p1 = acc * a[f], p2 = acc * a[64 + f];
    #pragma unroll
    for (int m = 32; m; m >>= 1){ p1 += __shfl_xor(p1, m, 64); p2 += __shfl_xor(p2, m, 64); }
    const int j = row0 + ry;
    if (f == 0){
        s1[j] = p1;
        F1[j] = __expf(p2); F2[j] = __expf(0.2f * p2);
    }
    const int sc = j >> 5, hg = (j >> 3) & 3, e = j & 7;
    const int fg = f >> 4, lr = f & 15;
    hpack[(((sc*4 + fg)*64) + hg*16 + lr)*8 + e] = __float2bfloat16(acc);
}

// K3: block = (jslab: 1024 cols) x (igrp: 256 rows). h-slab + F in LDS (136 KB).
// Loop's ONLY global traffic = 2 coalesced adj loads/step; 8-slot rotation with
// counted vmcnt(14) keeps ~7-8 KB/wave in flight; mask via in-register ballots.
// Shift-free factored softmax: Mr = 0 (softmax shift-invariant; fp32 range ok).
__global__ __launch_bounds__(512, 2) void k_gat(
    const float* __restrict__ adj, const float* __restrict__ s1g,
    const float* __restrict__ F1g, const float* __restrict__ F2g,
    const __hip_bfloat16* __restrict__ hpack,
    float* __restrict__ part, float* __restrict__ pden)
{
    __shared__ __attribute__((aligned(16))) char arena[139264]; // 128K hsl + 4K F1 + 4K F2

    const int tid = threadIdx.x;
    const int w = tid >> 6, lane = tid & 63;
    const int lr = lane & 15, hi = lane >> 4;
    const int jslab = blockIdx.x >> 5, igrp = blockIdx.x & 31;

    const s8* hsl = (const s8*)arena;
    float* F1sl = (float*)(arena + 131072);
    float* F2sl = (float*)(arena + 135168);

    // per-tile row constants (tiles A: rows rbA+0..15, B: rbA+128..143)
    const int rbA = igrp*256 + w*16;
    const int rowA = rbA + lr, rowB = rowA + 128;
    const float s1A = s1g[rowA], s1B = s1g[rowB];
    const float E1A = __expf(s1A), E2A = __expf(ALPHA*s1A), T1A = __expf(-s1A);
    const float E1B = __expf(s1B), E2B = __expf(ALPHA*s1B), T1B = __expf(-s1B);

    // stage h-slab (128 KB) via global_load_lds + F (8 KB)
    {
        const s8* hp = (const s8*)hpack + jslab*8192;
        #pragma unroll
        for (int it = 0; it < 16; ++it)
            gload_lds16(hp + w*1024 + it*64 + lane, arena + (w*1024 + it*64)*16);
        #pragma unroll
        for (int k = 0; k < 2; ++k){
            F1sl[tid + k*512] = F1g[jslab*1024 + tid + k*512];
            F2sl[tid + k*512] = F2g[jslab*1024 + tid + k*512];
        }
    }
    __syncthreads();   // drains staging; last barrier in the kernel

    // adj per-lane producer pointer: rows rbA + (lane>>3) (+8 for 2nd load), cols (lane&7)*4
    const float* padj = adj + (long)(rbA + (lane >> 3))*NROW + jslab*1024 + (lane & 7)*4;
    const unsigned bsh = (unsigned)((lr & 7)*8 + hi*2);
    const int hi8 = hi * 8;

    f4 acc0A={0,0,0,0}, acc1A={0,0,0,0}, acc2A={0,0,0,0}, acc3A={0,0,0,0};
    f4 acc0B={0,0,0,0}, acc1B={0,0,0,0}, acc2B={0,0,0,0}, acc3B={0,0,0,0};
    float lsumA = 0.f, lsumB = 0.f;

    f4 v0S0,v1S0, v0S1,v1S1, v0S2,v1S2, v0S3,v1S3;
    f4 v0S4,v1S4, v0S5,v1S5, v0S6,v1S6, v0S7,v1S7;

#define LOAD(S, st_) do { \
    const long o_ = (long)(((st_) >> 5) * (128*NROW)) + (((st_) & 31) * 32); \
    v0##S = *(const f4*)(padj + o_); \
    v1##S = *(const f4*)(padj + o_ + 8*NROW); \
} while(0)

#define CALCQ(X, cond, g1, g2, qd) { \
    float fz = ((g1) > T1##X) ? (g1) * E1##X : (g2) * E2##X; \
    qd = (cond) ? fz : 0.f; }

#define STEP(X, S, st_) do { \
    unsigned long long c0_ = __ballot(v0##S[0] > 0.f); \
    unsigned long long c1_ = __ballot(v0##S[1] > 0.f); \
    unsigned long long c2_ = __ballot(v0##S[2] > 0.f); \
    unsigned long long c3_ = __ballot(v0##S[3] > 0.f); \
    unsigned long long d0_ = __ballot(v1##S[0] > 0.f); \
    unsigned long long d1_ = __ballot(v1##S[1] > 0.f); \
    unsigned long long d2_ = __ballot(v1##S[2] > 0.f); \
    unsigned long long d3_ = __ballot(v1##S[3] > 0.f); \
    const unsigned u0 = (unsigned)(((lr < 8) ? c0_ : d0_) >> bsh); \
    const unsigned u1 = (unsigned)(((lr < 8) ? c1_ : d1_) >> bsh); \
    const unsigned u2 = (unsigned)(((lr < 8) ? c2_ : d2_) >> bsh); \
    const unsigned u3 = (unsigned)(((lr < 8) ? c3_ : d3_) >> bsh); \
    const int t_ = (st_) & 31; \
    const s8* hb_ = hsl + t_*256; \
    s8 h0 = hb_[lane]; s8 h1 = hb_[64 + lane]; \
    s8 h2 = hb_[128 + lane]; s8 h3 = hb_[192 + lane]; \
    f4 f1a = *(const f4*)&F1sl[t_*32 + hi8]; f4 f1b = *(const f4*)&F1sl[t_*32 + hi8 + 4]; \
    f4 f2a = *(const f4*)&F2sl[t_*32 + hi8]; f4 f2b = *(const f4*)&F2sl[t_*32 + hi8 + 4]; \
    float q0,q1,q2,q3,q4,q5,q6,q7; \
    CALCQ(X, u0 & 1u, f1a[0], f2a[0], q0); CALCQ(X, u1 & 1u, f1a[1], f2a[1], q1); \
    CALCQ(X, u2 & 1u, f1a[2], f2a[2], q2); CALCQ(X, u3 & 1u, f1a[3], f2a[3], q3); \
    CALCQ(X, u0 & 2u, f1b[0], f2b[0], q4); CALCQ(X, u1 & 2u, f1b[1], f2b[1], q5); \
    CALCQ(X, u2 & 2u, f1b[2], f2b[2], q6); CALCQ(X, u3 & 2u, f1b[3], f2b[3], q7); \
    lsum##X += ((q0+q1)+(q2+q3)) + ((q4+q5)+(q6+q7)); \
    s8 af; \
    af[0]=f2bf_bits(q0); af[1]=f2bf_bits(q1); af[2]=f2bf_bits(q2); af[3]=f2bf_bits(q3); \
    af[4]=f2bf_bits(q4); af[5]=f2bf_bits(q5); af[6]=f2bf_bits(q6); af[7]=f2bf_bits(q7); \
    acc0##X = __builtin_amdgcn_mfma_f32_16x16x32_bf16(af, h0, acc0##X, 0, 0, 0); \
    acc1##X = __builtin_amdgcn_mfma_f32_16x16x32_bf16(af, h1, acc1##X, 0, 0, 0); \
    acc2##X = __builtin_amdgcn_mfma_f32_16x16x32_bf16(af, h2, acc2##X, 0, 0, 0); \
    acc3##X = __builtin_amdgcn_mfma_f32_16x16x32_bf16(af, h3, acc3##X, 0, 0, 0); \
} while(0)

#define W14 asm volatile("s_waitcnt vmcnt(14)" ::: "memory")

    LOAD(S0, 0); LOAD(S1, 1); LOAD(S2, 2); LOAD(S3, 3);
    LOAD(S4, 4); LOAD(S5, 5); LOAD(S6, 6); LOAD(S7, 7);

#define ROUND(X, it_) do { \
    const int st = (it_)*8; \
    W14; STEP(X, S0, st    ); LOAD(S0, st + 8); \
    W14; STEP(X, S1, st + 1); LOAD(S1, st + 9); \
    W14; STEP(X, S2, st + 2); LOAD(S2, st + 10); \
    W14; STEP(X, S3, st + 3); LOAD(S3, st + 11); \
    W14; STEP(X, S4, st + 4); LOAD(S4, st + 12); \
    W14; STEP(X, S5, st + 5); LOAD(S5, st + 13); \
    W14; STEP(X, S6, st + 6); LOAD(S6, st + 14); \
    W14; STEP(X, S7, st + 7); LOAD(S7, st + 15); \
} while(0)

    #pragma unroll 1
    for (int it = 0; it < 4; ++it) ROUND(A, it);      // steps 0..31
    #pragma unroll 1
    for (int it = 4; it < 7; ++it) ROUND(B, it);      // steps 32..55
    // tail: steps 56..63, no further loads
    W14;                                          STEP(B, S0, 56);
    asm volatile("s_waitcnt vmcnt(12)" ::: "memory"); STEP(B, S1, 57);
    asm volatile("s_waitcnt vmcnt(10)" ::: "memory"); STEP(B, S2, 58);
    asm volatile("s_waitcnt vmcnt(8)"  ::: "memory"); STEP(B, S3, 59);
    asm volatile("s_waitcnt vmcnt(6)"  ::: "memory"); STEP(B, S4, 60);
    asm volatile("s_waitcnt vmcnt(4)"  ::: "memory"); STEP(B, S5, 61);
    asm volatile("s_waitcnt vmcnt(2)"  ::: "memory"); STEP(B, S6, 62);
    asm volatile("s_waitcnt vmcnt(0)"  ::: "memory"); STEP(B, S7, 63);

#undef LOAD
#undef CALCQ
#undef STEP
#undef W14
#undef ROUND

    lsumA += __shfl_xor(lsumA, 16, 64); lsumA += __shfl_xor(lsumA, 32, 64);
    lsumB += __shfl_xor(lsumB, 16, 64); lsumB += __shfl_xor(lsumB, 32, 64);

    // partial stores (C layout: col = lr, row = hi*4 + r, col-block q*16)
    {
        const long pbA = ((long)jslab*NROW + rbA + hi*4)*64 + lr;
        const long pbB = pbA + 128L*64;
        #pragma unroll
        for (int r = 0; r < 4; ++r){
            part[pbA + r*64 +  0] = acc0A[r];
            part[pbA + r*64 + 16] = acc1A[r];
            part[pbA + r*64 + 32] = acc2A[r];
            part[pbA + r*64 + 48] = acc3A[r];
            part[pbB + r*64 +  0] = acc0B[r];
            part[pbB + r*64 + 16] = acc1B[r];
            part[pbB + r*64 + 32] = acc2B[r];
            part[pbB + r*64 + 48] = acc3B[r];
        }
        if (lane < 16){
            pden[jslab*NROW + rbA + lr]       = lsumA;
            pden[jslab*NROW + rbA + 128 + lr] = lsumB;
        }
    }
}

// K4: combine 8 jslab partials, divide, ELU, store out.
__global__ __launch_bounds__(256) void k_comb(
    const float* __restrict__ part, const float* __restrict__ pden,
    float* __restrict__ out)
{
    const int idx = blockIdx.x*256 + threadIdx.x;   // 8192*16
    const int i = idx >> 4, c4 = (idx & 15) << 2;
    f4 sa = {0.f,0.f,0.f,0.f}; float L = 0.f;
    #pragma unroll
    for (int s = 0; s < 8; ++s){
        sa += *(const f4*)&part[((long)s*NROW + i)*64 + c4];
        L  += pden[s*NROW + i];
    }
    const float inv = 1.f / L;
    f4 o;
    #pragma unroll
    for (int e = 0; e < 4; ++e){
        float v = sa[e] * inv;
        o[e] = (v > 0.f) ? v : expm1f(v);
    }
    *(f4*)&out[(long)i*64 + c4] = o;
}

extern "C" void kernel_launch(void* const* d_in, const int* in_sizes, int n_in,
                              void* d_out, int out_size, void* d_ws, size_t ws_size,
                              hipStream_t stream)
{
    const float* x   = (const float*)d_in[0];
    const float* adj = (const float*)d_in[1];
    const float* W   = (const float*)d_in[2];
    const float* a   = (const float*)d_in[3];
    float* out = (float*)d_out;

    char* ws = (char*)d_ws;
    float* s1   = (float*)(ws);                    // 32 KB
    float* F1   = (float*)(ws + 65536);            // 32 KB
    float* F2   = (float*)(ws + 98304);            // 32 KB
    __hip_bfloat16* hpack = (__hip_bfloat16*)(ws + 131328);   // 1 MB
    float* part = (float*)(ws + 1179904);          // 16 MB (8 x 8192 x 64)
    float* pden = (float*)(ws + 17957120);         // 256 KB (8 x 8192)

    k_proj <<<2048,  256, 0, stream>>>(x, W, a, s1, F1, F2, hpack);
    k_gat  <<< 256,  512, 0, stream>>>(adj, s1, F1, F2, hpack, part, pden);
    k_comb <<< 512,  256, 0, stream>>>(part, pden, out);
}

// Round 12
// 67.590 us; speedup vs baseline: 1.5662x; 1.0457x over previous
//
#include <hip/hip_runtime.h>
#include <hip/hip_bf16.h>

#define ALPHA 0.2f
#define NROW 8192

typedef __attribute__((ext_vector_type(4))) float f4;
typedef __attribute__((ext_vector_type(8))) short s8;

__device__ __forceinline__ short f2bf_bits(float x){
    __hip_bfloat16 b = __float2bfloat16(x);
    return __builtin_bit_cast(short, b);
}

__device__ __forceinline__ void gload_lds16(const void* g, void* l){
    __builtin_amdgcn_global_load_lds(
        (const __attribute__((address_space(1))) void*)g,
        (__attribute__((address_space(3))) void*)l, 16, 0, 0);
}

// K1: h = x@W ; s1 ; F1=exp(s2) ; F2=exp(0.2*s2) ;
// hpack in MFMA B-fragment order: s8-unit (sc*4+fg)*64 + (hg*16+lr), lane elem e
//   = h[j = sc*32 + hg*8 + e][f = fg*16 + lr]  (bf16)
// 256 blocks x 32 rows: W staged ONCE per block (was 8x).
__global__ __launch_bounds__(256) void k_proj(
    const float* __restrict__ x, const float* __restrict__ W, const float* __restrict__ a,
    float* __restrict__ s1,
    float* __restrict__ F1, float* __restrict__ F2, __hip_bfloat16* __restrict__ hpack)
{
    __shared__ float Wsh[128*64];   // 32 KB
    __shared__ float xsh[32*128];   // 16 KB
    const int t = threadIdx.x;
    const int f = t & 63, wq = t >> 6;
    const int row0 = blockIdx.x * 32;
    for (int i = t; i < 128*64; i += 256) Wsh[i] = W[i];
    for (int i = t; i < 32*128; i += 256) xsh[i] = x[row0*128 + i];
    __syncthreads();
    const float a1 = a[f], a2 = a[64 + f];
    #pragma unroll 1
    for (int rr = 0; rr < 8; ++rr){
        const int ry = wq*8 + rr;
        float acc = 0.f;
        #pragma unroll
        for (int k = 0; k < 128; ++k) acc = fmaf(xsh[ry*128 + k], Wsh[k*64 + f], acc);
        float p1 = acc * a1, p2 = acc * a2;
        #pragma unroll
        for (int m = 32; m; m >>= 1){ p1 += __shfl_xor(p1, m, 64); p2 += __shfl_xor(p2, m, 64); }
        const int j = row0 + ry;
        if (f == 0){
            s1[j] = p1;
            F1[j] = __expf(p2); F2[j] = __expf(0.2f * p2);
        }
        const int sc = j >> 5, hg = (j >> 3) & 3, e = j & 7;
        const int fg = f >> 4, lr = f & 15;
        hpack[(((sc*4 + fg)*64) + hg*16 + lr)*8 + e] = __float2bfloat16(acc);
    }
}

// K3: block = (jslab: 2048 cols) x (igrp: 128 rows). 4 sub-windows of 512 cols;
// h double-buffered 2x64KB (staged next-window at current-window start; raw
// s_barrier per sub-window, NO vmcnt drain -> adj pipeline unbroken 64 steps).
// F (16 KB) staged upfront. adj = only loop global traffic, 8 slots W14.
__global__ __launch_bounds__(512, 2) void k_gat(
    const float* __restrict__ adj, const float* __restrict__ s1g,
    const float* __restrict__ F1g, const float* __restrict__ F2g,
    const __hip_bfloat16* __restrict__ hpack,
    float* __restrict__ part, float* __restrict__ pden)
{
    __shared__ __attribute__((aligned(16))) char arena[147456]; // 2x64K h + 8K F1 + 8K F2

    const int tid = threadIdx.x;
    const int w = tid >> 6, lane = tid & 63;
    const int lr = lane & 15, hi = lane >> 4;
    const int jslab = blockIdx.x >> 6, igrp = blockIdx.x & 63;

    float* F1sl = (float*)(arena + 131072);
    float* F2sl = (float*)(arena + 139264);

    const int rbA = igrp*128 + w*16;
    const int row = rbA + lr;
    const float s1r = s1g[row];
    const float E1 = __expf(s1r), E2 = __expf(ALPHA*s1r), T1 = __expf(-s1r);

#define STAGEH(buf, sw_) do { \
    const s8* hp_ = (const s8*)hpack + (jslab*64 + (sw_)*16)*256 + w*512 + lane; \
    char* dst_ = arena + (buf)*65536 + (w*512)*16; \
    _Pragma("unroll") \
    for (int it_ = 0; it_ < 8; ++it_) \
        gload_lds16(hp_ + it_*64, dst_ + it_*1024); \
} while(0)

    // prologue: h sub-window 0 -> buf0, F full slab
    STAGEH(0, 0);
    *(f4*)&F1sl[tid*4] = *(const f4*)(F1g + jslab*2048 + tid*4);
    *(f4*)&F2sl[tid*4] = *(const f4*)(F2g + jslab*2048 + tid*4);
    __syncthreads();   // drains prologue staging

    // adj per-lane pointer: rows rbA + (lane>>3) (+8 for 2nd load), cols (lane&7)*4
    const float* padj = adj + (long)(rbA + (lane >> 3))*NROW + jslab*2048 + (lane & 7)*4;
    const unsigned bsh = (unsigned)((lr & 7)*8 + hi*2);
    const int hi8 = hi * 8;

    f4 acc0={0,0,0,0}, acc1={0,0,0,0}, acc2={0,0,0,0}, acc3={0,0,0,0};
    float lsum = 0.f;

    f4 v0S0,v1S0, v0S1,v1S1, v0S2,v1S2, v0S3,v1S3;
    f4 v0S4,v1S4, v0S5,v1S5, v0S6,v1S6, v0S7,v1S7;

#define LOAD(S, s_) do { \
    const int o_ = (s_) * 32; \
    v0##S = *(const f4*)(padj + o_); \
    v1##S = *(const f4*)(padj + o_ + 8*NROW); \
} while(0)

#define CALCQ(cond, g1, g2, qd) { \
    float fz = ((g1) > T1) ? (g1) * E1 : (g2) * E2; \
    qd = (cond) ? fz : 0.f; }

#define STEP(S, s_) do { \
    unsigned long long c0_ = __ballot(v0##S[0] > 0.f); \
    unsigned long long c1_ = __ballot(v0##S[1] > 0.f); \
    unsigned long long c2_ = __ballot(v0##S[2] > 0.f); \
    unsigned long long c3_ = __ballot(v0##S[3] > 0.f); \
    unsigned long long d0_ = __ballot(v1##S[0] > 0.f); \
    unsigned long long d1_ = __ballot(v1##S[1] > 0.f); \
    unsigned long long d2_ = __ballot(v1##S[2] > 0.f); \
    unsigned long long d3_ = __ballot(v1##S[3] > 0.f); \
    const unsigned u0 = (unsigned)(((lr < 8) ? c0_ : d0_) >> bsh); \
    const unsigned u1 = (unsigned)(((lr < 8) ? c1_ : d1_) >> bsh); \
    const unsigned u2 = (unsigned)(((lr < 8) ? c2_ : d2_) >> bsh); \
    const unsigned u3 = (unsigned)(((lr < 8) ? c3_ : d3_) >> bsh); \
    const s8* hb_ = (const s8*)(arena + (((s_) >> 4) & 1)*65536) + ((s_) & 15)*256; \
    s8 h0 = hb_[lane]; s8 h1 = hb_[64 + lane]; \
    s8 h2 = hb_[128 + lane]; s8 h3 = hb_[192 + lane]; \
    f4 f1a = *(const f4*)&F1sl[(s_)*32 + hi8]; f4 f1b = *(const f4*)&F1sl[(s_)*32 + hi8 + 4]; \
    f4 f2a = *(const f4*)&F2sl[(s_)*32 + hi8]; f4 f2b = *(const f4*)&F2sl[(s_)*32 + hi8 + 4]; \
    float q0,q1,q2,q3,q4,q5,q6,q7; \
    CALCQ(u0 & 1u, f1a[0], f2a[0], q0); CALCQ(u1 & 1u, f1a[1], f2a[1], q1); \
    CALCQ(u2 & 1u, f1a[2], f2a[2], q2); CALCQ(u3 & 1u, f1a[3], f2a[3], q3); \
    CALCQ(u0 & 2u, f1b[0], f2b[0], q4); CALCQ(u1 & 2u, f1b[1], f2b[1], q5); \
    CALCQ(u2 & 2u, f1b[2], f2b[2], q6); CALCQ(u3 & 2u, f1b[3], f2b[3], q7); \
    lsum += ((q0+q1)+(q2+q3)) + ((q4+q5)+(q6+q7)); \
    s8 af; \
    af[0]=f2bf_bits(q0); af[1]=f2bf_bits(q1); af[2]=f2bf_bits(q2); af[3]=f2bf_bits(q3); \
    af[4]=f2bf_bits(q4); af[5]=f2bf_bits(q5); af[6]=f2bf_bits(q6); af[7]=f2bf_bits(q7); \
    acc0 = __builtin_amdgcn_mfma_f32_16x16x32_bf16(af, h0, acc0, 0, 0, 0); \
    acc1 = __builtin_amdgcn_mfma_f32_16x16x32_bf16(af, h1, acc1, 0, 0, 0); \
    acc2 = __builtin_amdgcn_mfma_f32_16x16x32_bf16(af, h2, acc2, 0, 0, 0); \
    acc3 = __builtin_amdgcn_mfma_f32_16x16x32_bf16(af, h3, acc3, 0, 0, 0); \
} while(0)

#define W14 asm volatile("s_waitcnt vmcnt(14)" ::: "memory")
#define ROUND8(stb) do { \
    W14; STEP(S0, (stb)    ); LOAD(S0, (stb) + 8); \
    W14; STEP(S1, (stb) + 1); LOAD(S1, (stb) + 9); \
    W14; STEP(S2, (stb) + 2); LOAD(S2, (stb) + 10); \
    W14; STEP(S3, (stb) + 3); LOAD(S3, (stb) + 11); \
    W14; STEP(S4, (stb) + 4); LOAD(S4, (stb) + 12); \
    W14; STEP(S5, (stb) + 5); LOAD(S5, (stb) + 13); \
    W14; STEP(S6, (stb) + 6); LOAD(S6, (stb) + 14); \
    W14; STEP(S7, (stb) + 7); LOAD(S7, (stb) + 15); \
} while(0)

    LOAD(S0, 0); LOAD(S1, 1); LOAD(S2, 2); LOAD(S3, 3);
    LOAD(S4, 4); LOAD(S5, 5); LOAD(S6, 6); LOAD(S7, 7);

    #pragma unroll 1
    for (int sw = 0; sw < 3; ++sw){
        STAGEH((sw + 1) & 1, sw + 1);      // next sub-window's h; retires under W14s
        const int stb = sw * 16;
        ROUND8(stb); ROUND8(stb + 8);
        asm volatile("s_barrier" ::: "memory");   // raw: no vmcnt drain
    }
    ROUND8(48);
    // tail: steps 56..63, drain
    W14;                                              STEP(S0, 56);
    asm volatile("s_waitcnt vmcnt(12)" ::: "memory"); STEP(S1, 57);
    asm volatile("s_waitcnt vmcnt(10)" ::: "memory"); STEP(S2, 58);
    asm volatile("s_waitcnt vmcnt(8)"  ::: "memory"); STEP(S3, 59);
    asm volatile("s_waitcnt vmcnt(6)"  ::: "memory"); STEP(S4, 60);
    asm volatile("s_waitcnt vmcnt(4)"  ::: "memory"); STEP(S5, 61);
    asm volatile("s_waitcnt vmcnt(2)"  ::: "memory"); STEP(S6, 62);
    asm volatile("s_waitcnt vmcnt(0)"  ::: "memory"); STEP(S7, 63);

#undef LOAD
#undef CALCQ
#undef STEP
#undef W14
#undef ROUND8
#undef STAGEH

    lsum += __shfl_xor(lsum, 16, 64);
    lsum += __shfl_xor(lsum, 32, 64);

    // partial stores (C layout: col = lr, row = hi*4 + r, col-block q*16)
    {
        const long pb = ((long)jslab*NROW + rbA + hi*4)*64 + lr;
        #pragma unroll
        for (int r = 0; r < 4; ++r){
            part[pb + r*64 +  0] = acc0[r];
            part[pb + r*64 + 16] = acc1[r];
            part[pb + r*64 + 32] = acc2[r];
            part[pb + r*64 + 48] = acc3[r];
        }
        if (lane < 16) pden[jslab*NROW + rbA + lr] = lsum;
    }
}

// K4: combine 4 jslab partials, divide, ELU, store out.
__global__ __launch_bounds__(256) void k_comb(
    const float* __restrict__ part, const float* __restrict__ pden,
    float* __restrict__ out)
{
    const int idx = blockIdx.x*256 + threadIdx.x;   // 8192*16
    const int i = idx >> 4, c4 = (idx & 15) << 2;
    f4 sa = {0.f,0.f,0.f,0.f}; float L = 0.f;
    #pragma unroll
    for (int s = 0; s < 4; ++s){
        sa += *(const f4*)&part[((long)s*NROW + i)*64 + c4];
        L  += pden[s*NROW + i];
    }
    const float inv = 1.f / L;
    f4 o;
    #pragma unroll
    for (int e = 0; e < 4; ++e){
        float v = sa[e] * inv;
        o[e] = (v > 0.f) ? v : expm1f(v);
    }
    *(f4*)&out[(long)i*64 + c4] = o;
}

extern "C" void kernel_launch(void* const* d_in, const int* in_sizes, int n_in,
                              void* d_out, int out_size, void* d_ws, size_t ws_size,
                              hipStream_t stream)
{
    const float* x   = (const float*)d_in[0];
    const float* adj = (const float*)d_in[1];
    const float* W   = (const float*)d_in[2];
    const float* a   = (const float*)d_in[3];
    float* out = (float*)d_out;

    char* ws = (char*)d_ws;
    float* s1   = (float*)(ws);                    // 32 KB
    float* F1   = (float*)(ws + 65536);            // 32 KB
    float* F2   = (float*)(ws + 98304);            // 32 KB
    __hip_bfloat16* hpack = (__hip_bfloat16*)(ws + 131328);   // 1 MB
    float* part = (float*)(ws + 1179904);          // 8 MB (4 x 8192 x 64)
    float* pden = (float*)(ws + 9568512);          // 128 KB (4 x 8192)

    k_proj <<<256, 256, 0, stream>>>(x, W, a, s1, F1, F2, hpack);
    k_gat  <<<256, 512, 0, stream>>>(adj, s1, F1, F2, hpack, part, pden);
    k_comb <<<512, 256, 0, stream>>>(part, pden, out);
}